// Round 6
// baseline (743.159 us; speedup 1.0000x reference)
//
#include <hip/hip_runtime.h>

// N=50000, E=600000, IN_CH=128, EDGE_DIM=64, OUT_CH=128
// edge_index delivered as int32.
//
// R12: ELIMINATE msgl (150MB write + 150MB read + 107us kernel). One fused
// edge kernel over the sorted position space:
//   block = 64 sorted edges (9375 blocks). Per 16-edge tile x ch-half
//   wave-unit (R7's proven independent-gather shape): gather ea rows (random
//   256B reads = the permutation), MFMA vs folded We@Wm (UNswapped layout so
//   each LDS-accumulate instruction hits 16 consecutive channels of one node
//   -> conflict-free, R6-proven), add gathered ub[src], leaky, accumulate
//   into a 32-node LDS window (64 sorted edges span ~7 nodes; overflow ->
//   direct global atomic). Flush nonzero slots to f32 agg via atomics.
// finalize kernel: out = sigmoid(agg) * relu(beta).

#define NB 25000
#define NB_SHIFT 1
#define EPB 64          // edges per block in edge_fused
#define LSLOT 32        // LDS node window

typedef __bf16 bf16x8 __attribute__((ext_vector_type(8)));
typedef float  f32x4  __attribute__((ext_vector_type(4)));
typedef unsigned short ushort_t;
typedef unsigned int   uint_t;

__device__ __forceinline__ ushort_t f2b(float f) {   // RNE f32->bf16
    uint_t u = __float_as_uint(f);
    u += 0x7FFF + ((u >> 16) & 1);
    return (ushort_t)(u >> 16);
}
__device__ __forceinline__ uint_t pack2(float a, float b) {
    return (uint_t)f2b(a) | ((uint_t)f2b(b) << 16);
}
__device__ __forceinline__ float b2f(ushort_t v) {
    return __uint_as_float((uint_t)v << 16);
}

// ---------------------------------------------------------------------------
// K1: fold weights -> bf16 k-major tables + f32 bias.
// ---------------------------------------------------------------------------
__global__ void fuse_weights_kernel(const float* __restrict__ Wx,
                                    const float* __restrict__ bx,
                                    const float* __restrict__ We,
                                    const float* __restrict__ be,
                                    const float* __restrict__ Wm,
                                    const float* __restrict__ bm,
                                    ushort_t* __restrict__ WxmT16,
                                    ushort_t* __restrict__ WemT16,
                                    float* __restrict__ bf) {
    int idx = blockIdx.x * blockDim.x + threadIdx.x;
    if (idx < 128 * 128) {
        int r = idx >> 7, c = idx & 127;       // r=k, c=ch
        float acc = 0.f;
        #pragma unroll 8
        for (int j = 0; j < 128; ++j) acc += Wx[r * 128 + j] * Wm[j * 128 + c];
        WxmT16[c * 128 + r] = f2b(acc);
    } else if (idx < 128 * 128 + 64 * 128) {
        int t = idx - 128 * 128;
        int r = t >> 7, c = t & 127;           // r=k(<64), c=ch
        float acc = 0.f;
        #pragma unroll 8
        for (int j = 0; j < 128; ++j) acc += We[r * 128 + j] * Wm[(128 + j) * 128 + c];
        WemT16[c * 64 + r] = f2b(acc);
    } else if (idx < 128 * 128 + 64 * 128 + 128) {
        int c = idx - (128 * 128 + 64 * 128);
        float acc = bm[c];
        #pragma unroll 8
        for (int j = 0; j < 128; ++j)
            acc += bx[j] * Wm[j * 128 + c] + be[j] * Wm[(128 + j) * 128 + c];
        bf[c] = acc;
    }
}

// ---------------------------------------------------------------------------
// K3: ub = bf16(x @ WxmT16 + bf). Operand-swapped MFMA -> packed uint2 stores.
// ---------------------------------------------------------------------------
__global__ __launch_bounds__(256) void node_gemm_kernel(
        const float* __restrict__ x, const ushort_t* __restrict__ WxmT16,
        const float* __restrict__ bf, ushort_t* __restrict__ ub, int N) {
    int tid = threadIdx.x;
    int g = blockIdx.x * 4 + (tid >> 6);
    if (g >= (N / 16) * 2) return;
    int lane = tid & 63, l15 = lane & 15, quad = lane >> 4;
    int n0 = (g >> 1) * 16;
    int chBase = (g & 1) * 64;

    bf16x8 B[4][4];
    #pragma unroll
    for (int ct = 0; ct < 4; ++ct)
        #pragma unroll
        for (int kk = 0; kk < 4; ++kk)
            B[ct][kk] = __builtin_bit_cast(bf16x8, *((const uint4*)
                &WxmT16[(size_t)(chBase + ct * 16 + l15) * 128 + kk * 32 + quad * 8]));

    bf16x8 A[4];
    #pragma unroll
    for (int kk = 0; kk < 4; ++kk) {
        const float4* s = (const float4*)&x[(size_t)(n0 + l15) * 128 + kk * 32 + quad * 8];
        float4 v0 = s[0], v1 = s[1];
        uint4 w;
        w.x = pack2(v0.x, v0.y);
        w.y = pack2(v0.z, v0.w);
        w.z = pack2(v1.x, v1.y);
        w.w = pack2(v1.z, v1.w);
        A[kk] = __builtin_bit_cast(bf16x8, w);
    }

    f32x4 acc[4] = {{0.f,0.f,0.f,0.f},{0.f,0.f,0.f,0.f},
                    {0.f,0.f,0.f,0.f},{0.f,0.f,0.f,0.f}};
    #pragma unroll
    for (int kk = 0; kk < 4; ++kk)
        #pragma unroll
        for (int ct = 0; ct < 4; ++ct)
            acc[ct] = __builtin_amdgcn_mfma_f32_16x16x32_bf16(B[ct][kk], A[kk], acc[ct], 0, 0, 0);

    #pragma unroll
    for (int ct = 0; ct < 4; ++ct) {
        int ch = chBase + ct * 16 + quad * 4;
        float4 bv = *(const float4*)&bf[ch];
        uint2 w;
        w.x = pack2(acc[ct][0] + bv.x, acc[ct][1] + bv.y);
        w.y = pack2(acc[ct][2] + bv.z, acc[ct][3] + bv.w);
        *((uint2*)&ub[(size_t)(n0 + l15) * 128 + ch]) = w;
    }
}

// ---------------------------------------------------------------------------
// K4: global-atomic histogram of dst buckets.
// ---------------------------------------------------------------------------
__global__ __launch_bounds__(256) void hist_kernel(
        const int* __restrict__ ei, int* __restrict__ cnt, int E) {
    int e = blockIdx.x * 256 + threadIdx.x;
    if (e < E) atomicAdd(&cnt[ei[E + e] >> NB_SHIFT], 1);
}

// ---------------------------------------------------------------------------
// K5: exclusive scan of cnt -> cur. Single block, 25 elems/thread.
// ---------------------------------------------------------------------------
__global__ __launch_bounds__(1024) void scan_kernel(
        const int* __restrict__ cnt, int* __restrict__ cur, int nb) {
    __shared__ int tot[1024];
    int t = threadIdx.x;
    int v[25]; int sum = 0;
    #pragma unroll
    for (int j = 0; j < 25; ++j) {
        int i = t * 25 + j;
        v[j] = (i < nb) ? cnt[i] : 0;
        sum += v[j];
    }
    tot[t] = sum;
    __syncthreads();
    for (int d = 1; d < 1024; d <<= 1) {
        int val = tot[t];
        int add = (t >= d) ? tot[t - d] : 0;
        __syncthreads();
        tot[t] = val + add;
        __syncthreads();
    }
    int ex = (t == 0) ? 0 : tot[t - 1];
    #pragma unroll
    for (int j = 0; j < 25; ++j) {
        int i = t * 25 + j;
        if (i < nb) cur[i] = ex;
        ex += v[j];
    }
}

// ---------------------------------------------------------------------------
// K6: global-atomic rank-and-place. rec64[p] = {orig_e, src | dst<<16}.
// (src < 65536 and dst < 65536 both hold: N = 50000.)
// ---------------------------------------------------------------------------
__global__ __launch_bounds__(256) void binpos_kernel(
        const int* __restrict__ ei, int* __restrict__ cur,
        uint2* __restrict__ rec64, int E) {
    int e = blockIdx.x * 256 + threadIdx.x;
    if (e >= E) return;
    int d = ei[E + e];
    int b = d >> NB_SHIFT;
    int p = atomicAdd(&cur[b], 1);
    uint2 r;
    r.x = (uint_t)e;
    r.y = (uint_t)ei[e] | ((uint_t)d << 16);
    rec64[p] = r;
}

// ---------------------------------------------------------------------------
// K8: FUSED edge GEMM + u-gather + reduction over sorted positions.
// Block = EPB sorted edges; 4 waves x 2 wave-units (16-edge tile x ch-half).
// Un-swapped MFMA layout (lane holds ch=l15, edge=quad*4+r) so every LDS
// accumulate instruction hits 16 consecutive channels -> conflict-free.
// ---------------------------------------------------------------------------
__global__ __launch_bounds__(256) void edge_fused_kernel(
        const float* __restrict__ ea, const uint2* __restrict__ rec64,
        const ushort_t* __restrict__ WemT16, const ushort_t* __restrict__ ub,
        float* __restrict__ agg, int E) {
    __shared__ float accum[LSLOT * 132];   // 16.9 KB, +4 pad vs 128

    int tid = threadIdx.x;
    int p0 = blockIdx.x * EPB;
    int p1 = p0 + EPB; if (p1 > E) p1 = E;

    for (int i = tid; i < LSLOT * 132; i += 256) accum[i] = 0.f;

    int w = tid >> 6, lane = tid & 63;
    int l15 = lane & 15, quad = lane >> 4;
    int chBase = (w & 1) << 6;

    // weight fragments for this wave's channel half (shared by both units)
    bf16x8 B[4][2];
    #pragma unroll
    for (int ct = 0; ct < 4; ++ct)
        #pragma unroll
        for (int kk = 0; kk < 2; ++kk)
            B[ct][kk] = __builtin_bit_cast(bf16x8, *((const uint4*)
                &WemT16[(size_t)(chBase + ct * 16 + l15) * 64 + kk * 32 + quad * 8]));

    int node_lo = (int)(rec64[p0].y >> 16) & ~1;   // bucket-aligned window base

    __syncthreads();   // accum zeroed

    #pragma unroll
    for (int ui = 0; ui < 2; ++ui) {
        int tile = (w >> 1) + ui * 2;              // 0..3
        int pt = p0 + tile * 16;
        if (pt >= E) continue;

        int p = pt + l15;
        uint2 rec = rec64[p < E ? p : (E - 1)];

        // gather this lane's edge row (edge slot l15), 4x float4
        const float* rowp = &ea[(size_t)rec.x * 64];
        const float4* sA = (const float4*)(rowp + quad * 8);
        float4 v0 = sA[0], v1 = sA[1];
        const float4* sB = (const float4*)(rowp + 32 + quad * 8);
        float4 v2 = sB[0], v3 = sB[1];
        uint4 w0, w1;
        w0.x = pack2(v0.x, v0.y);
        w0.y = pack2(v0.z, v0.w);
        w0.z = pack2(v1.x, v1.y);
        w0.w = pack2(v1.z, v1.w);
        w1.x = pack2(v2.x, v2.y);
        w1.y = pack2(v2.z, v2.w);
        w1.z = pack2(v3.x, v3.y);
        w1.w = pack2(v3.z, v3.w);
        bf16x8 a0 = __builtin_bit_cast(bf16x8, w0);
        bf16x8 a1 = __builtin_bit_cast(bf16x8, w1);

        f32x4 acc[4] = {{0.f,0.f,0.f,0.f},{0.f,0.f,0.f,0.f},
                        {0.f,0.f,0.f,0.f},{0.f,0.f,0.f,0.f}};
        #pragma unroll
        for (int ct = 0; ct < 4; ++ct)
            acc[ct] = __builtin_amdgcn_mfma_f32_16x16x32_bf16(a0, B[ct][0], acc[ct], 0, 0, 0);
        #pragma unroll
        for (int ct = 0; ct < 4; ++ct)
            acc[ct] = __builtin_amdgcn_mfma_f32_16x16x32_bf16(a1, B[ct][1], acc[ct], 0, 0, 0);

        int me = E - pt;   // valid edges in this tile (>=1)
        #pragma unroll
        for (int r = 0; r < 4; ++r) {
            int mm = quad * 4 + r;                 // edge index within tile
            uint_t ry = __shfl(rec.y, mm);         // src|dst of edge mm
            int sr = (int)(ry & 0xFFFFu);
            int dst = (int)(ry >> 16);
            int nl = dst - node_lo;
            bool vm = mm < me;
            #pragma unroll
            for (int ct = 0; ct < 4; ++ct) {
                int ch = chBase + ct * 16 + l15;
                float m = acc[ct][r] + b2f(ub[(size_t)sr * 128 + ch]);
                m = fmaxf(m, 0.01f * m);           // leaky relu
                if (vm) {
                    if (nl < LSLOT)
                        atomicAdd(&accum[nl * 132 + ch], m);
                    else
                        atomicAdd(&agg[(size_t)dst * 128 + ch], m);
                }
            }
        }
    }
    __syncthreads();

    // flush nonzero window slots to global agg
    int node_hi = ((int)(rec64[p1 - 1].y >> 16)) | 1;
    int span = node_hi - node_lo + 1;
    if (span > LSLOT) span = LSLOT;
    for (int i = tid; i < span * 128; i += 256) {
        int nl = i >> 7, c = i & 127;
        float v = accum[nl * 132 + c];
        if (v != 0.f) atomicAdd(&agg[(size_t)(node_lo + nl) * 128 + c], v);
    }
}

// ---------------------------------------------------------------------------
// K9: out = sigmoid(agg) * relu(beta).
// ---------------------------------------------------------------------------
__global__ __launch_bounds__(256) void finalize_kernel(
        const float* __restrict__ agg, const float* __restrict__ beta,
        float* __restrict__ out, int n4) {
    int gid = blockIdx.x * 256 + threadIdx.x;
    if (gid >= n4) return;
    float rb = beta[0];
    rb = rb > 0.f ? rb : 0.f;
    float4 v = ((const float4*)agg)[gid];
    v.x = rb / (1.f + __expf(-v.x));
    v.y = rb / (1.f + __expf(-v.y));
    v.z = rb / (1.f + __expf(-v.z));
    v.w = rb / (1.f + __expf(-v.w));
    ((float4*)out)[gid] = v;
}

// ---------------------------------------------------------------------------
extern "C" void kernel_launch(void* const* d_in, const int* in_sizes, int n_in,
                              void* d_out, int out_size, void* d_ws, size_t ws_size,
                              hipStream_t stream) {
    const float* x    = (const float*)d_in[0];
    const int*   ei   = (const int*)d_in[1];
    const float* ea   = (const float*)d_in[2];
    const float* Wx   = (const float*)d_in[3];
    const float* bx   = (const float*)d_in[4];
    const float* We   = (const float*)d_in[5];
    const float* be   = (const float*)d_in[6];
    const float* Wm   = (const float*)d_in[7];
    const float* bm   = (const float*)d_in[8];
    const float* beta = (const float*)d_in[9];

    int N = in_sizes[0] / 128;   // 50000
    int E = in_sizes[2] / 64;    // 600000

    float* out = (float*)d_out;

    // workspace layout (bytes)
    char* ws = (char*)d_ws;
    ushort_t* WxmT16 = (ushort_t*)(ws);                    // 32768
    ushort_t* WemT16 = (ushort_t*)(ws + 32768);            // 16384
    float*    bf     = (float*)(ws + 49152);               // 512
    ushort_t* ub     = (ushort_t*)(ws + 65536);            // 12.8 MB (bf16)
    size_t off = 65536 + (size_t)N * 128 * 2;
    uint2* rec64   = (uint2*)(ws + off);                   // 4.8 MB
    off += (size_t)E * 8;
    int* cnt       = (int*)(ws + off);                     // 100 KB
    int* cur       = (int*)(ws + off + 131072);            // 100 KB
    float* agg     = (float*)(ws + off + 262144);          // 25.6 MB (f32)

    hipMemsetAsync(cnt, 0, (size_t)NB * sizeof(int), stream);
    hipMemsetAsync(agg, 0, (size_t)N * 128 * sizeof(float), stream);

    fuse_weights_kernel<<<(24704 + 255) / 256, 256, 0, stream>>>(
        Wx, bx, We, be, Wm, bm, WxmT16, WemT16, bf);

    node_gemm_kernel<<<(N / 16 * 2 + 3) / 4, 256, 0, stream>>>(
        x, WxmT16, bf, ub, N);

    int ebBlocks = (E + 255) / 256;   // 2344
    hist_kernel<<<ebBlocks, 256, 0, stream>>>(ei, cnt, E);
    scan_kernel<<<1, 1024, 0, stream>>>(cnt, cur, NB);
    binpos_kernel<<<ebBlocks, 256, 0, stream>>>(ei, cur, rec64, E);

    int fBlocks = (E + EPB - 1) / EPB;   // 9375
    edge_fused_kernel<<<fBlocks, 256, 0, stream>>>(
        ea, rec64, WemT16, ub, agg, E);

    int n4 = N * 32;   // 1.6M float4
    finalize_kernel<<<(n4 + 255) / 256, 256, 0, stream>>>(agg, beta, out, n4);
}